// Round 4
// baseline (25193.611 us; speedup 1.0000x reference)
//
#include <hip/hip_runtime.h>
#include <hip/hip_bf16.h>

// Problem constants
#define NSEQ 320     // 256 tran sub-seqs + 32 doc_anchor + 32 doc_neg
#define NTRAN 256
#define TT 128       // tran T
#define TDOC 256     // doc T
#define EH 512       // E == H == 512

#define WT_SZ (1024*2048)            // wT: [k=0..1023][row=0..2047]
#define AWT_SZ (512*512)
#define SC_W 258

// ---- module-global scratch (guaranteed mapped at module load) ----
__device__ float g_wT[2*WT_SZ];      // [tran|doc][k][row]
__device__ float g_awT[2*AWT_SZ];    // [tran|doc][k][j]
__device__ float g_h[3*NSEQ*EH];     // h ring buffer [slot][seq][j]
__device__ float g_c[NSEQ*EH];
__device__ float g_acc[NSEQ*EH];     // online-softmax numerator
__device__ float g_ml[16*NSEQ*2];    // per-(j_tile,seq) {m,l}
__device__ float g_sc[NSEQ*SC_W];    // attention scores
__device__ float g_pool[NSEQ*EH];
__device__ float g_loss;

#define FMA4(A, W, S) { (A).x = fmaf((W).x,(S),(A).x); (A).y = fmaf((W).y,(S),(A).y); \
                        (A).z = fmaf((W).z,(S),(A).z); (A).w = fmaf((W).w,(S),(A).w); }

__device__ __forceinline__ float sigm(float x) { return 1.0f / (1.0f + expf(-x)); }

__device__ __forceinline__ int seq_token(int s, int t, const int* __restrict__ tran,
                                         const int* __restrict__ da, const int* __restrict__ dn) {
  if (s < NTRAN) return tran[s*TT + t];
  if (s < NTRAN+32) return da[(s-NTRAN)*TDOC + t];
  return dn[(s-NTRAN-32)*TDOC + t];
}
__device__ __forceinline__ int seq_len(int s, const int* __restrict__ tbl,
                                       const int* __restrict__ dal, const int* __restrict__ dnl) {
  if (s < NTRAN) return tbl[s];
  if (s < NTRAN+32) return dal[s-NTRAN];
  return dnl[s-NTRAN-32];
}

// ---------------- sentinel: FLOAT 2.0 (diagnoses late-kernel failure; overwritten at end) ----
__global__ void sentinel_kernel(float* __restrict__ out) {
  if (threadIdx.x == 0) out[0] = 2.0f;
}

// ---------------- init state each call (deterministic across replays) ----------------
__global__ __launch_bounds__(256) void init_state() {
  int i = blockIdx.x*256 + threadIdx.x;
  if (i < 3*NSEQ*EH) g_h[i] = 0.0f;
  if (i < NSEQ*EH)  { g_c[i] = 0.0f; g_acc[i] = 0.0f; }
  if (i < NSEQ*SC_W) g_sc[i] = 0.0f;
  if (i < 16*NSEQ*2) g_ml[i] = (i & 1) ? 0.0f : -3.0e38f;
  if (i == 0) g_loss = 0.0f;
}

// ---------------- build transposed weights: wT[k][row], awT[k][j] ----------------
__global__ __launch_bounds__(256) void build_wt(
    const float* __restrict__ wih_t, const float* __restrict__ whh_t,
    const float* __restrict__ wih_d, const float* __restrict__ whh_d,
    const float* __restrict__ aw_t,  const float* __restrict__ aw_d) {
  int idx = blockIdx.x*256 + threadIdx.x;
  const int NW = WT_SZ;
  if (idx < 2*NW) {
    int p = idx / NW; int r2 = idx % NW;
    int k = r2 / 2048; int r = r2 % 2048;
    const float* wih = p ? wih_d : wih_t;
    const float* whh = p ? whh_d : whh_t;
    float v = (k < 512) ? wih[r*512 + k] : whh[r*512 + (k - 512)];
    g_wT[p*NW + k*2048 + r] = v;
  } else {
    idx -= 2*NW;
    if (idx < 2*AWT_SZ) {
      int p = idx / AWT_SZ; int q = idx % AWT_SZ;
      int k = q / 512; int j = q % 512;
      const float* aw = p ? aw_d : aw_t;
      g_awT[p*AWT_SZ + k*512 + j] = aw[j*512 + k];
    }
  }
}

// ---------------- per-timestep fused kernel ----------------
// Block = (n_tile of 16 seqs, j_tile of 32 h-columns). 256 threads. LDS = 40KB.
// Phase A: score partials for h_{t-1}  (atomicAdd -> sc[s][t-1], finalized at kernel boundary)
// Phase B: online-softmax acc update for h_{t-2} using finalized sc[s][t-2]
// Phase C: gates + c/h update for step t
__global__ __launch_bounds__(256) void step_kernel(
    int t, int ntile_base,
    const int* __restrict__ tran, const int* __restrict__ tbl,
    const int* __restrict__ da_tok, const int* __restrict__ dal,
    const int* __restrict__ dn_tok, const int* __restrict__ dnl,
    const float* __restrict__ emb,
    const float* __restrict__ b_tran,  const float* __restrict__ b_doc,
    const float* __restrict__ ab_tran, const float* __restrict__ ab_doc,
    const float* __restrict__ sw_tran, const float* __restrict__ sw_doc,
    const float* __restrict__ sb_tran, const float* __restrict__ sb_doc) {
  __shared__ __hip_bfloat16 xh[16][1024];   // [seq_local][x(512) | h_prev(512)] as bf16: 32KB
  __shared__ float gbuf[4][16][32];         // gate exchange: 8KB

  const int tid = threadIdx.x;
  const int nt = ntile_base + (int)blockIdx.x / 16;
  const int jt = (int)blockIdx.x % 16;
  const int sbase = nt * 16;
  const bool isdoc = (sbase >= NTRAN);
  const int Ts = isdoc ? TDOC : TT;

  const float* wT   = g_wT  + (isdoc ? WT_SZ  : 0);
  const float* awT  = g_awT + (isdoc ? AWT_SZ : 0);
  const float* bias = isdoc ? b_doc   : b_tran;
  const float* ab   = isdoc ? ab_doc  : ab_tran;
  const float* sw   = isdoc ? sw_doc  : sw_tran;
  const float  sb   = isdoc ? sb_doc[0] : sb_tran[0];

  const int hp = (t + 2) % 3;   // h_{t-1}
  const int hc = t % 3;         // h_t (written)
  const int h2 = (t + 1) % 3;   // h_{t-2}

  // ---- stage x_t and h_{t-1} into LDS as bf16 ----
  if (t <= Ts) {
    for (int i = tid; i < 16*128; i += 256) {   // each i: 8 floats -> 8 bf16 (16B store)
      int n = i >> 7; int c8 = i & 127;         // k = c8*8
      int s = sbase + n;
      float4 v0 = make_float4(0.f,0.f,0.f,0.f), v1 = v0;
      if (c8 < 64) {
        if (t < Ts) {
          int tok = seq_token(s, t, tran, da_tok, dn_tok);
          const float* src = &emb[(long)tok*EH + c8*8];
          v0 = *(const float4*)src; v1 = *(const float4*)(src + 4);
        }
      } else {
        const float* src = &g_h[(hp*NSEQ + s)*EH + (c8 - 64)*8];
        v0 = *(const float4*)src; v1 = *(const float4*)(src + 4);
      }
      __hip_bfloat16 tmp[8];
      tmp[0]=__float2bfloat16(v0.x); tmp[1]=__float2bfloat16(v0.y);
      tmp[2]=__float2bfloat16(v0.z); tmp[3]=__float2bfloat16(v0.w);
      tmp[4]=__float2bfloat16(v1.x); tmp[5]=__float2bfloat16(v1.y);
      tmp[6]=__float2bfloat16(v1.z); tmp[7]=__float2bfloat16(v1.w);
      *(uint4*)&xh[n][c8*8] = *(const uint4*)tmp;
    }
  }
  __syncthreads();

  // ---- Phase A: attention score partials for h_{t-1} ----
  if (t >= 1 && (t - 1) < Ts) {
    int jl = tid & 31; int n0 = tid >> 5;    // n0 in 0..7, also handles n0+8
    int jg = jt*32 + jl;
    float u0 = ab[jg], u1 = ab[jg];
    for (int k = 0; k < 512; k++) {
      float a = awT[k*512 + jg];
      u0 = fmaf(__bfloat162float(xh[n0][512 + k]), a, u0);
      u1 = fmaf(__bfloat162float(xh[n0 + 8][512 + k]), a, u1);
    }
    float swv = sw[jg];
    float p0 = tanhf(u0) * swv;
    float p1 = tanhf(u1) * swv;
    #pragma unroll
    for (int off = 16; off >= 1; off >>= 1) {
      p0 += __shfl_xor(p0, off, 64);
      p1 += __shfl_xor(p1, off, 64);
    }
    if (jl == 0) {
      float extra = (jt == 0) ? sb : 0.0f;
      atomicAdd(&g_sc[(sbase + n0)*SC_W + (t - 1)], p0 + extra);
      atomicAdd(&g_sc[(sbase + n0 + 8)*SC_W + (t - 1)], p1 + extra);
    }
  }

  // ---- Phase B: online-softmax accumulate h_{t-2} ----
  if (t >= 2) {
    int jl = tid & 31; int n0 = tid >> 5;
    #pragma unroll
    for (int rep = 0; rep < 2; rep++) {
      int n = n0 + rep*8; int s = sbase + n;
      int len = seq_len(s, tbl, dal, dnl);
      if ((t - 2) < len) {
        float sval = g_sc[s*SC_W + (t - 2)];
        float* mlp = &g_ml[(jt*NSEQ + s)*2];
        float m_old = mlp[0], l_old = mlp[1];
        float m_new = fmaxf(m_old, sval);
        float alpha = expf(m_old - m_new);     // 0 on first valid step
        float e = expf(sval - m_new);
        int jg = jt*32 + jl;
        float hv = g_h[(h2*NSEQ + s)*EH + jg];
        g_acc[s*EH + jg] = g_acc[s*EH + jg]*alpha + e*hv;
        if (jl == 0) { mlp[0] = m_new; mlp[1] = l_old*alpha + e; }
      }
    }
  }

  // ---- Phase C: gates for step t ----
  if (t < Ts) {
    int j4g = tid & 7;          // 4-wide j group within the 32-j tile
    int g   = (tid >> 3) & 3;   // gate: 0=i 1=f 2=g 3=o
    int n0  = tid >> 5;         // 0..7, also n0+8
    int jb  = jt*32 + j4g*4;
    int row = g*512 + jb;
    float4 a0 = *(const float4*)&bias[row];
    float4 a1 = a0;
    const float* wp = wT + row;
    #pragma unroll 4
    for (int k = 0; k < 1024; k++) {
      float x0 = __bfloat162float(xh[n0][k]);
      float x1 = __bfloat162float(xh[n0 + 8][k]);
      float4 w = *(const float4*)&wp[k*2048];
      FMA4(a0, w, x0);
      FMA4(a1, w, x1);
    }
    *(float4*)&gbuf[g][n0][j4g*4] = a0;
    *(float4*)&gbuf[g][n0 + 8][j4g*4] = a1;
  }
  __syncthreads();
  if (t < Ts) {
    int jl = tid & 31; int n0 = tid >> 5;
    #pragma unroll
    for (int rep = 0; rep < 2; rep++) {
      int n = n0 + rep*8; int s = sbase + n;
      float gi = gbuf[0][n][jl];
      float gf = gbuf[1][n][jl];
      float gg = gbuf[2][n][jl];
      float go = gbuf[3][n][jl];
      int jg = jt*32 + jl;
      float cv = g_c[s*EH + jg];
      float cn = sigm(gf)*cv + sigm(gi)*tanhf(gg);
      float hn = sigm(go)*tanhf(cn);
      g_c[s*EH + jg] = cn;
      g_h[(hc*NSEQ + s)*EH + jg] = hn;
    }
  }
}

// ---------------- finalize pooled = acc / l  (tanh on tran path) ----------------
__global__ __launch_bounds__(256) void finalize_pool() {
  int s = blockIdx.x;
  float l = g_ml[s*2 + 1];   // j_tile 0 copy
  for (int j = threadIdx.x; j < EH; j += 256) {
    float v = g_acc[s*EH + j] / l;
    if (s < NTRAN) v = tanhf(v);
    g_pool[s*EH + j] = v;
  }
}

// ---------------- per-batch cosine terms + loss accumulate ----------------
__global__ __launch_bounds__(256) void loss_partial() {
  __shared__ float red[5][4];
  int b = blockIdx.x, tid = threadIdx.x;
  float p[5] = {0.f, 0.f, 0.f, 0.f, 0.f};
  for (int j = tid; j < EH; j += 256) {
    float m = -3.0e38f;
    #pragma unroll
    for (int bl = 0; bl < 8; bl++) m = fmaxf(m, g_pool[(b*8 + bl)*EH + j]);
    float da = g_pool[(NTRAN + b)*EH + j];
    float dn = g_pool[(NTRAN + 32 + b)*EH + j];
    p[0] += m*m; p[1] += da*da; p[2] += dn*dn; p[3] += m*da; p[4] += m*dn;
  }
  int lane = tid & 63, w = tid >> 6;
  #pragma unroll
  for (int i = 0; i < 5; i++) {
    float v = p[i];
    for (int off = 32; off >= 1; off >>= 1) v += __shfl_xor(v, off, 64);
    if (lane == 0) red[i][w] = v;
  }
  __syncthreads();
  if (tid == 0) {
    float cc = red[0][0] + red[0][1] + red[0][2] + red[0][3];
    float aa = red[1][0] + red[1][1] + red[1][2] + red[1][3];
    float nn = red[2][0] + red[2][1] + red[2][2] + red[2][3];
    float ca = red[3][0] + red[3][1] + red[3][2] + red[3][3];
    float cn = red[4][0] + red[4][1] + red[4][2] + red[4][3];
    float ncr = fmaxf(sqrtf(cc), 1e-8f);
    float nda = fmaxf(sqrtf(aa), 1e-8f);
    float ndn = fmaxf(sqrtf(nn), 1e-8f);
    float simA = ca / (ncr * nda);
    float simN = cn / (ncr * ndn);
    float term = fmaxf(0.05f - simA + simN, 1e-6f);
    atomicAdd(&g_loss, term * (1.0f / 32.0f));
  }
}

// ---------------- FLOAT output (reference output dtype is float32!) ----------------
__global__ void write_out(float* __restrict__ out) {
  if (threadIdx.x == 0 && blockIdx.x == 0) out[0] = g_loss;
}

extern "C" void kernel_launch(void* const* d_in, const int* in_sizes, int n_in,
                              void* d_out, int out_size, void* d_ws, size_t ws_size,
                              hipStream_t stream) {
  (void)in_sizes; (void)n_in; (void)out_size; (void)d_ws; (void)ws_size;
  const int*   tran   = (const int*)d_in[0];
  const int*   tbl    = (const int*)d_in[2];   // tran_block_len (tran_len d_in[1] unused by ref)
  const int*   da_tok = (const int*)d_in[3];
  const int*   dal    = (const int*)d_in[4];
  const int*   dn_tok = (const int*)d_in[5];
  const int*   dnl    = (const int*)d_in[6];
  const float* emb    = (const float*)d_in[7];
  const float* wih_t  = (const float*)d_in[8];
  const float* whh_t  = (const float*)d_in[9];
  const float* b_t    = (const float*)d_in[10];
  const float* wih_d  = (const float*)d_in[11];
  const float* whh_d  = (const float*)d_in[12];
  const float* b_d    = (const float*)d_in[13];
  const float* aw_t   = (const float*)d_in[14];
  const float* ab_t   = (const float*)d_in[15];
  const float* sw_t   = (const float*)d_in[16];
  const float* sb_t   = (const float*)d_in[17];
  const float* aw_d   = (const float*)d_in[18];
  const float* ab_d   = (const float*)d_in[19];
  const float* sw_d   = (const float*)d_in[20];
  const float* sb_d   = (const float*)d_in[21];

  // sentinel FIRST (float 2.0): if final output reads ~2.0, late kernels failed;
  // exact-ref error again would mean true infrastructure failure.
  sentinel_kernel<<<1, 64, 0, stream>>>((float*)d_out);

  init_state<<<(3*NSEQ*EH + 255) / 256, 256, 0, stream>>>();
  build_wt<<<(2*WT_SZ + 2*AWT_SZ + 255) / 256, 256, 0, stream>>>(
      wih_t, whh_t, wih_d, whh_d, aw_t, aw_d);

  // steps: t=0..257.  t<=129 covers tran (gates to 127, score 128, acc 129) + doc.
  // t>=130: doc tiles only (n_tile 16..19).
  for (int t = 0; t <= 257; t++) {
    int nb   = (t <= 129) ? 320 : 64;
    int base = (t <= 129) ? 0 : 16;
    step_kernel<<<nb, 256, 0, stream>>>(
        t, base, tran, tbl, da_tok, dal, dn_tok, dnl, emb,
        b_t, b_d, ab_t, ab_d, sw_t, sw_d, sb_t, sb_d);
  }

  finalize_pool<<<NSEQ, 256, 0, stream>>>();
  loss_partial<<<32, 256, 0, stream>>>();
  write_out<<<1, 64, 0, stream>>>((float*)d_out);
}

// Round 5
// 16081.732 us; speedup vs baseline: 1.5666x; 1.5666x over previous
//
#include <hip/hip_runtime.h>
#include <hip/hip_bf16.h>

// Problem constants
#define NSEQ 320     // 256 tran sub-seqs + 32 doc_anchor + 32 doc_neg
#define NTRAN 256
#define TT 128       // tran T
#define TDOC 256     // doc T
#define EH 512       // E == H == 512

#define WT_SZ (1024*2048)            // wT: [k=0..1023][row=0..2047]
#define AWT_SZ (512*512)             // awT: [k][j]
#define SC_W 258

// ---- module-global scratch ----
__device__ float g_wT[2*WT_SZ];      // [tran|doc][k][row]  (k-major for coalesced per-k reads)
__device__ float g_awT[2*AWT_SZ];    // [tran|doc][k][j]
__device__ float g_h[3*NSEQ*EH];     // h ring buffer [slot][seq][j]
__device__ float g_c[NSEQ*EH];
__device__ float g_acc[NSEQ*EH];     // online-softmax numerator
__device__ float g_ml[16*NSEQ*2];    // per-(j_tile,seq) {m,l}
__device__ float g_sc[NSEQ*SC_W];    // attention scores
__device__ float g_pool[NSEQ*EH];
__device__ float g_loss;

__device__ __forceinline__ float sigm(float x) { return 1.0f / (1.0f + expf(-x)); }

__device__ __forceinline__ int seq_token(int s, int t, const int* __restrict__ tran,
                                         const int* __restrict__ da, const int* __restrict__ dn) {
  if (s < NTRAN) return tran[s*TT + t];
  if (s < NTRAN+32) return da[(s-NTRAN)*TDOC + t];
  return dn[(s-NTRAN-32)*TDOC + t];
}
__device__ __forceinline__ int seq_len(int s, const int* __restrict__ tbl,
                                       const int* __restrict__ dal, const int* __restrict__ dnl) {
  if (s < NTRAN) return tbl[s];
  if (s < NTRAN+32) return dal[s-NTRAN];
  return dnl[s-NTRAN-32];
}

// ---------------- init state each call ----------------
__global__ __launch_bounds__(256) void init_state() {
  int i = blockIdx.x*256 + threadIdx.x;
  if (i < 3*NSEQ*EH) g_h[i] = 0.0f;
  if (i < NSEQ*EH)  { g_c[i] = 0.0f; g_acc[i] = 0.0f; }
  if (i < NSEQ*SC_W) g_sc[i] = 0.0f;
  if (i < 16*NSEQ*2) g_ml[i] = (i & 1) ? 0.0f : -3.0e38f;
  if (i == 0) g_loss = 0.0f;
}

// ---------------- build transposed weights: wT[k][row], awT[k][j] ----------------
__global__ __launch_bounds__(256) void build_wt(
    const float* __restrict__ wih_t, const float* __restrict__ whh_t,
    const float* __restrict__ wih_d, const float* __restrict__ whh_d,
    const float* __restrict__ aw_t,  const float* __restrict__ aw_d) {
  int idx = blockIdx.x*256 + threadIdx.x;
  const int NW = WT_SZ;
  if (idx < 2*NW) {
    int p = idx / NW; int r2 = idx % NW;
    int k = r2 / 2048; int r = r2 % 2048;
    const float* wih = p ? wih_d : wih_t;
    const float* whh = p ? whh_d : whh_t;
    float v = (k < 512) ? wih[r*512 + k] : whh[r*512 + (k - 512)];
    g_wT[p*NW + k*2048 + r] = v;
  } else {
    idx -= 2*NW;
    if (idx < 2*AWT_SZ) {
      int p = idx / AWT_SZ; int q = idx % AWT_SZ;
      int k = q / 512; int j = q % 512;
      const float* aw = p ? aw_d : aw_t;
      g_awT[p*AWT_SZ + k*512 + j] = aw[j*512 + k];
    }
  }
}

// ---------------- per-timestep fused kernel ----------------
// Block = (n_tile of 16 seqs, j_tile of 32 h-cols = 128 gate rows). 256 threads. LDS = 80KB
// => 2 blocks/CU. Weight reads are k-major & coalesced with ZERO intra-block redundancy.
// xh operand: LDS f32 [16][1024], read as wave-uniform b128 broadcasts (conflict-free).
// Phase A: score partials for h_{t-1} (k split 8 ways, LDS-reduced, then atomicAdd)
// Phase B: online-softmax acc update for h_{t-2} (scores finalized at kernel boundary)
// Phase C: gates (k split 2 ways, LDS-reduced) + c/h update for step t
__global__ __launch_bounds__(256) void step_kernel(
    int t, int ntile_base,
    const int* __restrict__ tran, const int* __restrict__ tbl,
    const int* __restrict__ da_tok, const int* __restrict__ dal,
    const int* __restrict__ dn_tok, const int* __restrict__ dnl,
    const float* __restrict__ emb,
    const float* __restrict__ b_tran,  const float* __restrict__ b_doc,
    const float* __restrict__ ab_tran, const float* __restrict__ ab_doc,
    const float* __restrict__ sw_tran, const float* __restrict__ sw_doc,
    const float* __restrict__ sb_tran, const float* __restrict__ sb_doc) {
  __shared__ float xh[16][1024];   // 64KB: [seq][x(512)|h(512)]
  __shared__ float red[4096];      // 16KB: A-partials [8][16][32] / C-partials [2][128][16]

  const int tid = threadIdx.x;
  const int nt = ntile_base + (int)blockIdx.x / 16;
  const int jt = (int)blockIdx.x % 16;
  const int sbase = nt * 16;
  const bool isdoc = (sbase >= NTRAN);
  const int Ts = isdoc ? TDOC : TT;

  const float* wT   = g_wT  + (isdoc ? WT_SZ  : 0);
  const float* awT  = g_awT + (isdoc ? AWT_SZ : 0);
  const float* bias = isdoc ? b_doc   : b_tran;
  const float* ab   = isdoc ? ab_doc  : ab_tran;
  const float* sw   = isdoc ? sw_doc  : sw_tran;
  const float  sb   = isdoc ? sb_doc[0] : sb_tran[0];

  const int hp = (t + 2) % 3;   // h_{t-1}
  const int hc = t % 3;         // h_t (written)
  const int h2 = (t + 1) % 3;   // h_{t-2}

  // ---- stage x_t ‖ h_{t-1} into LDS (f32, conflict-free b128 stores) ----
  if (t <= Ts) {
    for (int i = tid; i < 16*256; i += 256) {
      int n = i >> 8; int c4 = i & 255;
      int s = sbase + n;
      float4 v = make_float4(0.f, 0.f, 0.f, 0.f);
      if (c4 < 128) {
        if (t < Ts) {
          int tok = seq_token(s, t, tran, da_tok, dn_tok);
          v = *(const float4*)&emb[tok*EH + c4*4];
        }
      } else {
        v = *(const float4*)&g_h[(hp*NSEQ + s)*EH + (c4 - 128)*4];
      }
      *(float4*)&xh[n][c4*4] = v;
    }
  }
  __syncthreads();

  const bool doA = (t >= 1) && ((t - 1) < Ts);

  // ---- Phase A partials: u[n][j] = sum_k h[n][k]*aw[j][k], k split 8 ways ----
  if (doA) {
    int jl = tid & 31; int kga = tid >> 5;     // kga 0..7, 64 k each
    int col = jt*32 + jl;
    float ua[16];
    #pragma unroll
    for (int n = 0; n < 16; ++n) ua[n] = 0.f;
    #pragma unroll 2
    for (int kq = 0; kq < 16; ++kq) {
      int kp = kga*64 + kq*4;                  // h-space k' in [0,512)
      float a0 = awT[(kp+0)*512 + col];
      float a1 = awT[(kp+1)*512 + col];
      float a2 = awT[(kp+2)*512 + col];
      float a3 = awT[(kp+3)*512 + col];
      #pragma unroll
      for (int n = 0; n < 16; ++n) {
        float4 xv = *(const float4*)&xh[n][512 + kp];   // broadcast read
        ua[n] = fmaf(a0, xv.x, ua[n]); ua[n] = fmaf(a1, xv.y, ua[n]);
        ua[n] = fmaf(a2, xv.z, ua[n]); ua[n] = fmaf(a3, xv.w, ua[n]);
      }
    }
    #pragma unroll
    for (int n = 0; n < 16; ++n) red[(kga*16 + n)*32 + jl] = ua[n];
  }
  __syncthreads();

  // ---- Phase A finish: reduce over kga, tanh*sw, sum over j (shuffle), atomicAdd ----
  if (doA) {
    int jl = tid & 31; int n0 = tid >> 5;
    int jg = jt*32 + jl;
    float u0 = ab[jg], u1 = ab[jg];
    #pragma unroll
    for (int kga = 0; kga < 8; ++kga) {
      u0 += red[(kga*16 + n0)*32 + jl];
      u1 += red[(kga*16 + n0 + 8)*32 + jl];
    }
    float swv = sw[jg];
    float p0 = tanhf(u0) * swv;
    float p1 = tanhf(u1) * swv;
    #pragma unroll
    for (int off = 16; off >= 1; off >>= 1) {
      p0 += __shfl_xor(p0, off, 64);
      p1 += __shfl_xor(p1, off, 64);
    }
    if (jl == 0) {
      float extra = (jt == 0) ? sb : 0.0f;
      atomicAdd(&g_sc[(sbase + n0)*SC_W + (t - 1)], p0 + extra);
      atomicAdd(&g_sc[(sbase + n0 + 8)*SC_W + (t - 1)], p1 + extra);
    }
  }

  // ---- Phase B: online-softmax accumulate h_{t-2} (global only, no LDS) ----
  if (t >= 2) {
    int jl = tid & 31; int n0 = tid >> 5;
    #pragma unroll
    for (int rep = 0; rep < 2; rep++) {
      int n = n0 + rep*8; int s = sbase + n;
      int len = seq_len(s, tbl, dal, dnl);
      if ((t - 2) < len) {
        float sval = g_sc[s*SC_W + (t - 2)];
        float* mlp = &g_ml[(jt*NSEQ + s)*2];
        float m_old = mlp[0], l_old = mlp[1];
        float m_new = fmaxf(m_old, sval);
        float alpha = expf(m_old - m_new);
        float e = expf(sval - m_new);
        int jg = jt*32 + jl;
        float hv = g_h[(h2*NSEQ + s)*EH + jg];
        g_acc[s*EH + jg] = g_acc[s*EH + jg]*alpha + e*hv;
        if (jl == 0) { mlp[0] = m_new; mlp[1] = l_old*alpha + e; }
      }
    }
  }

  __syncthreads();   // A-finish reads of red[] done before Phase C overwrites

  // ---- Phase C: gates. thread = (row r of 128, k-half kg). Weights read once per block. ----
  if (t < Ts) {
    int r  = tid & 127;
    int kg = tid >> 7;                          // 0..1, 512 k each
    int col = ((r >> 5) << 9) + jt*32 + (r & 31);   // gate*512 + j
    float acc[16];
    #pragma unroll
    for (int n = 0; n < 16; ++n) acc[n] = 0.f;
    #pragma unroll 2
    for (int k4 = kg*128; k4 < kg*128 + 128; ++k4) {
      int k = k4*4;
      float w0 = wT[(k+0)*2048 + col];          // lanes -> consecutive cols: coalesced
      float w1 = wT[(k+1)*2048 + col];
      float w2 = wT[(k+2)*2048 + col];
      float w3 = wT[(k+3)*2048 + col];
      #pragma unroll
      for (int n = 0; n < 16; ++n) {
        float4 xv = *(const float4*)&xh[n][k];  // wave-uniform broadcast
        acc[n] = fmaf(w0, xv.x, acc[n]); acc[n] = fmaf(w1, xv.y, acc[n]);
        acc[n] = fmaf(w2, xv.z, acc[n]); acc[n] = fmaf(w3, xv.w, acc[n]);
      }
    }
    #pragma unroll
    for (int n2 = 0; n2 < 4; ++n2) {
      *(float4*)&red[(kg*128 + r)*16 + n2*4] =
        make_float4(acc[n2*4], acc[n2*4+1], acc[n2*4+2], acc[n2*4+3]);
    }
  }
  __syncthreads();

  // ---- reduce k-halves + bias -> gate pre-activations (in place, thread-owned) ----
  if (t < Ts) {
    int r = tid >> 1; int n0 = (tid & 1) * 8;
    int row = ((r >> 5) << 9) + jt*32 + (r & 31);
    float b = bias[row];
    float4 s0 = *(const float4*)&red[r*16 + n0];
    float4 s1 = *(const float4*)&red[r*16 + n0 + 4];
    float4 t0 = *(const float4*)&red[(128 + r)*16 + n0];
    float4 t1 = *(const float4*)&red[(128 + r)*16 + n0 + 4];
    *(float4*)&red[r*16 + n0]     = make_float4(b+s0.x+t0.x, b+s0.y+t0.y, b+s0.z+t0.z, b+s0.w+t0.w);
    *(float4*)&red[r*16 + n0 + 4] = make_float4(b+s1.x+t1.x, b+s1.y+t1.y, b+s1.z+t1.z, b+s1.w+t1.w);
  }
  __syncthreads();

  // ---- c/h update ----
  if (t < Ts) {
    int jl = tid & 31; int n0 = tid >> 5;
    #pragma unroll
    for (int rep = 0; rep < 2; rep++) {
      int n = n0 + rep*8; int s = sbase + n;
      float gi = red[((0*32) + jl)*16 + n];
      float gf = red[((1*32) + jl)*16 + n];
      float gg = red[((2*32) + jl)*16 + n];
      float go = red[((3*32) + jl)*16 + n];
      int jg = jt*32 + jl;
      float cv = g_c[s*EH + jg];
      float cn = sigm(gf)*cv + sigm(gi)*tanhf(gg);
      float hn = sigm(go)*tanhf(cn);
      g_c[s*EH + jg] = cn;
      g_h[(hc*NSEQ + s)*EH + jg] = hn;
    }
  }
}

// ---------------- finalize pooled = acc / l  (tanh on tran path) ----------------
__global__ __launch_bounds__(256) void finalize_pool() {
  int s = blockIdx.x;
  float l = g_ml[s*2 + 1];   // j_tile 0 copy
  for (int j = threadIdx.x; j < EH; j += 256) {
    float v = g_acc[s*EH + j] / l;
    if (s < NTRAN) v = tanhf(v);
    g_pool[s*EH + j] = v;
  }
}

// ---------------- per-batch cosine terms + loss accumulate ----------------
__global__ __launch_bounds__(256) void loss_partial() {
  __shared__ float red[5][4];
  int b = blockIdx.x, tid = threadIdx.x;
  float p[5] = {0.f, 0.f, 0.f, 0.f, 0.f};
  for (int j = tid; j < EH; j += 256) {
    float m = -3.0e38f;
    #pragma unroll
    for (int bl = 0; bl < 8; bl++) m = fmaxf(m, g_pool[(b*8 + bl)*EH + j]);
    float da = g_pool[(NTRAN + b)*EH + j];
    float dn = g_pool[(NTRAN + 32 + b)*EH + j];
    p[0] += m*m; p[1] += da*da; p[2] += dn*dn; p[3] += m*da; p[4] += m*dn;
  }
  int lane = tid & 63, w = tid >> 6;
  #pragma unroll
  for (int i = 0; i < 5; i++) {
    float v = p[i];
    for (int off = 32; off >= 1; off >>= 1) v += __shfl_xor(v, off, 64);
    if (lane == 0) red[i][w] = v;
  }
  __syncthreads();
  if (tid == 0) {
    float cc = red[0][0] + red[0][1] + red[0][2] + red[0][3];
    float aa = red[1][0] + red[1][1] + red[1][2] + red[1][3];
    float nn = red[2][0] + red[2][1] + red[2][2] + red[2][3];
    float ca = red[3][0] + red[3][1] + red[3][2] + red[3][3];
    float cn = red[4][0] + red[4][1] + red[4][2] + red[4][3];
    float ncr = fmaxf(sqrtf(cc), 1e-8f);
    float nda = fmaxf(sqrtf(aa), 1e-8f);
    float ndn = fmaxf(sqrtf(nn), 1e-8f);
    float simA = ca / (ncr * nda);
    float simN = cn / (ncr * ndn);
    float term = fmaxf(0.05f - simA + simN, 1e-6f);
    atomicAdd(&g_loss, term * (1.0f / 32.0f));
  }
}

// ---------------- FLOAT output (reference output dtype is float32) ----------------
__global__ void write_out(float* __restrict__ out) {
  if (threadIdx.x == 0 && blockIdx.x == 0) out[0] = g_loss;
}

extern "C" void kernel_launch(void* const* d_in, const int* in_sizes, int n_in,
                              void* d_out, int out_size, void* d_ws, size_t ws_size,
                              hipStream_t stream) {
  (void)in_sizes; (void)n_in; (void)out_size; (void)d_ws; (void)ws_size;
  const int*   tran   = (const int*)d_in[0];
  const int*   tbl    = (const int*)d_in[2];   // tran_block_len (tran_len unused by ref)
  const int*   da_tok = (const int*)d_in[3];
  const int*   dal    = (const int*)d_in[4];
  const int*   dn_tok = (const int*)d_in[5];
  const int*   dnl    = (const int*)d_in[6];
  const float* emb    = (const float*)d_in[7];
  const float* wih_t  = (const float*)d_in[8];
  const float* whh_t  = (const float*)d_in[9];
  const float* b_t    = (const float*)d_in[10];
  const float* wih_d  = (const float*)d_in[11];
  const float* whh_d  = (const float*)d_in[12];
  const float* b_d    = (const float*)d_in[13];
  const float* aw_t   = (const float*)d_in[14];
  const float* ab_t   = (const float*)d_in[15];
  const float* sw_t   = (const float*)d_in[16];
  const float* sb_t   = (const float*)d_in[17];
  const float* aw_d   = (const float*)d_in[18];
  const float* ab_d   = (const float*)d_in[19];
  const float* sw_d   = (const float*)d_in[20];
  const float* sb_d   = (const float*)d_in[21];

  init_state<<<(3*NSEQ*EH + 255) / 256, 256, 0, stream>>>();
  build_wt<<<(2*WT_SZ + 2*AWT_SZ + 255) / 256, 256, 0, stream>>>(
      wih_t, whh_t, wih_d, whh_d, aw_t, aw_d);

  // steps: t=0..257.  t<=129: tran (gates to 127, score at 128, acc at 129) + doc.
  // t>=130: doc tiles only (n_tile 16..19).
  for (int t = 0; t <= 257; t++) {
    int nb   = (t <= 129) ? 320 : 64;
    int base = (t <= 129) ? 0 : 16;
    step_kernel<<<nb, 256, 0, stream>>>(
        t, base, tran, tbl, da_tok, dal, dn_tok, dnl, emb,
        b_t, b_d, ab_t, ab_d, sw_t, sw_d, sb_t, sb_d);
  }

  finalize_pool<<<NSEQ, 256, 0, stream>>>();
  loss_partial<<<32, 256, 0, stream>>>();
  write_out<<<1, 64, 0, stream>>>((float*)d_out);
}